// Round 2
// baseline (580.690 us; speedup 1.0000x reference)
//
#include <hip/hip_runtime.h>
#include <math.h>

#define BB 32
#define HH 12
#define CC 512
#define DD 768
#define MM 8
#define NERD 6
#define NCLS 97
#define KTOT 1542        // 2*D + NER
#define KMAIN 1536       // 2*D (ner tail handled in epilogue)
#define OFFS 1
#define KCH 192          // K-chunk staged in LDS (8 chunks * 192 = 1536)
#define APAD 194         // LDS row stride: (194*b)%32 = 2b -> 2-way (free)

// ---------------------------------------------------------------------------
// ws layout (float offsets):
//   raw     [B*C]        @ 0        (zeroed)  un-normalized ht_att
//   Sb      [B]          @ 16384              sum_c raw
//   rs_part [B*32*D]     @ 16416              partial rs over 32 c-chunks
//   Afull   [B*1536]     @ 802848             concat(hs, rs_norm) per b
//   fbuf    [2*B*D]      @ 852000             tanh'd head (e=0) / tail (e=1)
// total ~901k floats = 3.6 MB
// ---------------------------------------------------------------------------

// grid (B, 13), block 512.
// h < 12: ht_att accumulation — contrib (sum_m a0)(sum_m a1)/(M*M*H).
// h == 12: hs = logsumexp over the M e=0 mention rows -> Afull[b][0..768).
__global__ void k_att(const float* __restrict__ att, const float* __restrict__ seq,
                      const int* __restrict__ epos, float* __restrict__ raw,
                      float* __restrict__ Afull) {
    int b = blockIdx.x, h = blockIdx.y;
    __shared__ int pos[16];
    if (threadIdx.x < 16) pos[threadIdx.x] = epos[b * 16 + threadIdx.x] + OFFS;
    __syncthreads();
    if (h < HH) {
        int c = threadIdx.x;
        const float* base = att + ((size_t)(b * HH + h)) * CC * CC;
        float a0 = 0.f, a1 = 0.f;
#pragma unroll
        for (int m = 0; m < MM; m++) {
            a0 += base[(size_t)pos[m] * CC + c];
            a1 += base[(size_t)pos[MM + m] * CC + c];
        }
        atomicAdd(&raw[b * CC + c], a0 * a1 * (1.0f / (MM * MM * HH)));
        return;
    }
    // h == 12: logsumexp, 192 active threads x float4
    int t = threadIdx.x;
    if (t >= 192) return;
    float xs0[MM], xs1[MM], xs2[MM], xs3[MM];
#pragma unroll
    for (int m = 0; m < MM; m++) {
        float4 v = *(const float4*)&seq[((size_t)b * CC + pos[m]) * DD + t * 4];
        xs0[m] = v.x; xs1[m] = v.y; xs2[m] = v.z; xs3[m] = v.w;
    }
    float o[4];
    float* xs[4] = {xs0, xs1, xs2, xs3};
#pragma unroll
    for (int comp = 0; comp < 4; comp++) {
        float mx = xs[comp][0];
#pragma unroll
        for (int m = 1; m < MM; m++) mx = fmaxf(mx, xs[comp][m]);
        float se = 0.f;
#pragma unroll
        for (int m = 0; m < MM; m++) se += expf(xs[comp][m] - mx);
        o[comp] = logf(se) + mx;
    }
    float4 hv = {o[0], o[1], o[2], o[3]};
    *(float4*)&Afull[(size_t)b * KMAIN + t * 4] = hv;
}

// rs partials: grid (B, 32), block 192; thread owns 4 d's (float4), loops 16 c.
// blocks with cc==0 also reduce S_b = sum_c raw[b,c].
__global__ void k_rs_part(const float* __restrict__ seq, const float* __restrict__ raw,
                          float* __restrict__ rs_part, float* __restrict__ Sb) {
    int b = blockIdx.x, cc = blockIdx.y, t = threadIdx.x;
    float4 acc = {0.f, 0.f, 0.f, 0.f};
    const float* rw = raw + b * CC + cc * 16;
    const float* sp = seq + ((size_t)b * CC + cc * 16) * DD + t * 4;
#pragma unroll 4
    for (int ci = 0; ci < 16; ci++) {
        float w = rw[ci];
        float4 v = *(const float4*)(sp + (size_t)ci * DD);
        acc.x += v.x * w; acc.y += v.y * w; acc.z += v.z * w; acc.w += v.w * w;
    }
    *(float4*)&rs_part[((size_t)(b * 32 + cc)) * DD + t * 4] = acc;
    if (cc == 0) {
        __shared__ float sb[192];
        float s = 0.f;
        for (int c = t; c < CC; c += 192) s += raw[b * CC + c];
        sb[t] = s;
        __syncthreads();
        if (t == 0) {
            float tot = 0.f;
            for (int i = 0; i < 192; i++) tot += sb[i];
            Sb[b] = tot;
        }
    }
}

// reduce 32 partials, normalize by (Sb + 1e-5), write into Afull[b][768..1536).
// grid B, block 192.
__global__ void k_rs_fin(const float* __restrict__ rs_part, const float* __restrict__ Sb,
                         float* __restrict__ Afull) {
    int b = blockIdx.x, t = threadIdx.x;
    float4 acc = {0.f, 0.f, 0.f, 0.f};
    for (int cc = 0; cc < 32; cc++) {
        float4 p = *(const float4*)&rs_part[((size_t)(b * 32 + cc)) * DD + t * 4];
        acc.x += p.x; acc.y += p.y; acc.z += p.z; acc.w += p.w;
    }
    float inv = 1.0f / (Sb[b] + 1e-5f);
    float4 r = {acc.x * inv, acc.y * inv, acc.z * inv, acc.w * inv};
    *(float4*)&Afull[(size_t)b * KMAIN + DD + t * 4] = r;
}

// head/tail GEMM + bias + tanh, no K-split, no atomics.
// grid (96, 2), block 256: thread (b = tid&31, jq = tid>>5) owns output (e,b, j=jt*8+jq).
// K-loop: 8 chunks of 192 staged in LDS; W read as even-aligned float2;
// ner tail (k=1536..1541) + bias + tanh in epilogue.
__global__ void k_headtail(const float* __restrict__ Afull, const float* __restrict__ ner,
                           const float* __restrict__ Wh, const float* __restrict__ bh,
                           const float* __restrict__ Wt, const float* __restrict__ bt,
                           float* __restrict__ fbuf) {
    int jt = blockIdx.x, e = blockIdx.y;
    int tid = threadIdx.x;
    int b = tid & 31, jq = tid >> 5;
    int j = jt * 8 + jq;
    const float* W = e ? Wt : Wh;
    const float* bias = e ? bt : bh;
    __shared__ float A[32][APAD];
    float acc = 0.f;
    for (int ch = 0; ch < 8; ch++) {
        for (int i = tid; i < 32 * KCH; i += 256) {
            int bb = i / KCH, kk = i - bb * KCH;
            A[bb][kk] = Afull[(size_t)bb * KMAIN + ch * KCH + kk];
        }
        __syncthreads();
        const float* Wrow = W + (size_t)j * KTOT + ch * KCH;  // even float offset -> 8B aligned
#pragma unroll 8
        for (int kk = 0; kk < KCH; kk += 2) {
            float2 w = *(const float2*)&Wrow[kk];
            float2 a = *(const float2*)&A[b][kk];
            acc += a.x * w.x + a.y * w.y;
        }
        __syncthreads();
    }
    const float* nr = ner + (b * 2 + e) * NERD;
    const float* Wn = W + (size_t)j * KTOT + KMAIN;
#pragma unroll
    for (int q = 0; q < NERD; q++) acc += nr[q] * Wn[q];
    fbuf[(size_t)(e * 32 + b) * DD + j] = tanhf(acc + bias[j]);
}

// bilinear + final matmul: grid NCLS, block 256 (32 b x 8 k-groups).
__global__ void k_bil(const float* __restrict__ fbuf, const float* __restrict__ Wb,
                      const float* __restrict__ bbil, float* __restrict__ out) {
    int n = blockIdx.x;
    int g = threadIdx.x & 7, b = threadIdx.x >> 3;
    const float* hsf = fbuf + b * DD;
    const float* tsf = fbuf + (32 + b) * DD;
    const float* W = Wb + (size_t)n * (DD * 8);
    float acc = 0.f;
    for (int t = 0; t < 12; t++) {
        int f = g + 8 * t;
        float4 h0 = *(const float4*)&hsf[f * 8];
        float4 h1 = *(const float4*)&hsf[f * 8 + 4];
        float4 t0 = *(const float4*)&tsf[f * 8];
        float4 t1 = *(const float4*)&tsf[f * 8 + 4];
        float hv[8] = {h0.x, h0.y, h0.z, h0.w, h1.x, h1.y, h1.z, h1.w};
        float tv[8] = {t0.x, t0.y, t0.z, t0.w, t1.x, t1.y, t1.z, t1.w};
        const float* wf = W + f * 64;
#pragma unroll
        for (int i = 0; i < 8; i++) {
            float4 w0 = *(const float4*)&wf[i * 8];
            float4 w1 = *(const float4*)&wf[i * 8 + 4];
            float dot = tv[0] * w0.x + tv[1] * w0.y + tv[2] * w0.z + tv[3] * w0.w
                      + tv[4] * w1.x + tv[5] * w1.y + tv[6] * w1.z + tv[7] * w1.w;
            acc += hv[i] * dot;
        }
    }
    __shared__ float part[32 * 9];
    part[b * 9 + g] = acc;
    __syncthreads();
    if (g == 0) {
        float s = 0.f;
#pragma unroll
        for (int i = 0; i < 8; i++) s += part[b * 9 + i];
        out[b * NCLS + n] = s + bbil[n];
    }
}

extern "C" void kernel_launch(void* const* d_in, const int* in_sizes, int n_in,
                              void* d_out, int out_size, void* d_ws, size_t ws_size,
                              hipStream_t stream) {
    const float* seq  = (const float*)d_in[0];
    const float* att  = (const float*)d_in[1];
    const float* ner  = (const float*)d_in[2];
    const float* Wh   = (const float*)d_in[3];
    const float* bh   = (const float*)d_in[4];
    const float* Wt   = (const float*)d_in[5];
    const float* bt   = (const float*)d_in[6];
    const float* Wbil = (const float*)d_in[7];
    const float* bbil = (const float*)d_in[8];
    const int*   epos = (const int*)d_in[9];
    float* out = (float*)d_out;
    float* ws = (float*)d_ws;

    float* raw     = ws;             // 16384 floats (zeroed)
    float* Sb      = ws + 16384;     // 32
    float* rs_part = ws + 16416;     // 32*32*768 = 786432
    float* Afull   = ws + 802848;    // 32*1536 = 49152
    float* fbuf    = ws + 852000;    // 2*32*768 = 49152

    hipMemsetAsync(raw, 0, (size_t)16384 * 4, stream);

    k_att<<<dim3(BB, HH + 1), 512, 0, stream>>>(att, seq, epos, raw, Afull);
    k_rs_part<<<dim3(BB, 32), 192, 0, stream>>>(seq, raw, rs_part, Sb);
    k_rs_fin<<<BB, 192, 0, stream>>>(rs_part, Sb, Afull);
    k_headtail<<<dim3(96, 2), 256, 0, stream>>>(Afull, ner, Wh, bh, Wt, bt, fbuf);
    k_bil<<<NCLS, 256, 0, stream>>>(fbuf, Wbil, bbil, out);
}